// Round 18
// baseline (90.312 us; speedup 1.0000x reference)
//
#include <hip/hip_runtime.h>

#define CH    128
#define HH    56
#define WW    56
#define BB    32
#define NPIX  (BB * HH * WW)   // 100352
#define NSLOT 16
#define TPB   4                // tiles (rows) per block
#define NBLK  (BB * HH / TPB)  // 448 blocks

#define XROW   7424            // 58 cols * 128 ci, bytes per padded row
#define XBATCH 430592          // 58 rows * XROW
#define LDSROW 8448            // 66 px * 128 B
#define SWZ(pl, ci) ((ci) ^ (((pl) & 7) << 4))

typedef int i32x4  __attribute__((ext_vector_type(4)));
typedef int i32x16 __attribute__((ext_vector_type(16)));

__device__ __forceinline__ void mfma_i8(i32x16& acc, i32x4 a, i32x4 b) {
    asm("v_mfma_i32_32x32x32_i8 %0, %1, %2, %0" : "+v"(acc) : "v"(a), "v"(b));
}

// ---------------- prep: xi8 signs + borders + wfrag + accum zero ----------------
// (verbatim from the passing R10..R17 kernels)
__global__ __launch_bounds__(256) void prep_k(const float* __restrict__ x,
                                              const float* __restrict__ Wt,
                                              signed char* __restrict__ xi8,
                                              signed char* __restrict__ wfrag,
                                              unsigned long long* __restrict__ accum) {
    int bx = blockIdx.x, tid = threadIdx.x;
    if (bx < 12544) {                       // interior signs: one float4 -> 4 int8
        int t = bx * 256 + tid;             // < 3,211,264
        int p = t >> 5;
        int ci0 = (t & 31) * 4;
        int w = p % WW;
        int t2 = p / WW;
        int h = t2 % HH;
        int b = t2 / HH;
        float4 v = ((const float4*)x)[t];
        unsigned o = (v.x >= 0.f ? 0x01u : 0xFFu)
                   | ((v.y >= 0.f ? 0x01u : 0xFFu) << 8)
                   | ((v.z >= 0.f ? 0x01u : 0xFFu) << 16)
                   | ((v.w >= 0.f ? 0x01u : 0xFFu) << 24);
        *(unsigned*)(xi8 + (size_t)b * XBATCH + (size_t)(h + 1) * XROW + (w + 1) * 128 + ci0) = o;
    } else if (bx < 12772) {                // border zeros: 58368 16B chunks
        int c = (bx - 12544) * 256 + tid;
        int cell = c >> 3, q = c & 7;
        int b = cell / 228, e = cell % 228;
        int row, col;
        if (e < 58)       { row = 0;       col = e; }
        else if (e < 116) { row = 57;      col = e - 58; }
        else if (e < 172) { row = e - 115; col = 0; }
        else              { row = e - 171; col = 57; }
        i32x4 z = {0, 0, 0, 0};
        *(i32x4*)(xi8 + (size_t)b * XBATCH + (size_t)row * XROW + col * 128 + q * 16) = z;
    } else if (bx < 12808) {                // wfrag: [n32][q=36][lane][16B]
        int i = (bx - 12772) * 256 + tid;   // < 9216
        int n = i / 2304;
        int r = i % 2304;
        int q = r / 64;
        int L = r % 64;
        int tap = q >> 2, kk = q & 3;
        int co = 32 * n + (L & 31);
        int kbase = 32 * kk + (L >> 5) * 16;
        i32x4 o;
        #pragma unroll
        for (int d = 0; d < 4; ++d) {
            unsigned u = 0;
            #pragma unroll
            for (int by = 0; by < 4; ++by) {
                int ci = kbase + 4 * d + by;
                unsigned s = (Wt[((size_t)tap * 128 + ci) * 128 + co] >= 0.f) ? 0x01u : 0xFFu;
                u |= s << (8 * by);
            }
            o[d] = (int)u;
        }
        *(i32x4*)(wfrag + (size_t)i * 16) = o;
    } else {                                // accum zero
        for (int k = tid; k < NSLOT * 256; k += 256) accum[k] = 0ull;
    }
}

// ---------------- gemm1: stats-only conv pass (448 blocks x 4 tiles) ----------------
__global__ __launch_bounds__(512) void gemm1_k(const signed char* __restrict__ xi8,
                                               const signed char* __restrict__ wfrag,
                                               unsigned long long* __restrict__ accum) {
    __shared__ alignas(16) char sm[4 * LDSROW];   // 33,792 B

    int ph0 = 1 + ((blockIdx.x * TPB) % HH);
    int b   = (blockIdx.x * TPB) / HH;

    int L = threadIdx.x & 63, w = threadIdx.x >> 6;
    int n32 = w & 3, sh = w >> 2;
    int l31 = L & 31, hi = L >> 5;

    int coff[3][4];
    #pragma unroll
    for (int dw = 0; dw < 3; ++dw) {
        int pld = l31 + dw;
        int pl = 32 * sh + pld;
        #pragma unroll
        for (int kk = 0; kk < 4; ++kk)
            coff[dw][kk] = pl * 128 + ((32 * kk + 16 * hi) ^ ((pld & 7) << 4));
    }

    const i32x4* bfp = (const i32x4*)wfrag + (size_t)n32 * 36 * 64;
    i32x4 bfr[36];
    #pragma unroll
    for (int q = 0; q < 36; ++q) bfr[q] = bfp[q * 64 + L];

    int co = 32 * n32 + l31;

    for (int c = threadIdx.x; c < 1392; c += 512) {
        int rr = c / 464;
        int off = (c % 464) * 16;
        int row = ph0 - 1 + rr;
        int p = off >> 7, ci0 = off & 127;
        i32x4 v = *(const i32x4*)(xi8 + (size_t)b * XBATCH + (size_t)row * XROW + off);
        int pl = p + 1;
        *(i32x4*)(sm + (row & 3) * LDSROW + pl * 128 + SWZ(pl, ci0)) = v;
    }
    if (threadIdx.x < 256) {
        int slot = threadIdx.x >> 6, g = threadIdx.x & 63;
        int gp = g >> 3, ci0 = (g & 7) * 16;
        int pl = (gp == 0) ? 0 : (58 + gp);
        i32x4 z = {0, 0, 0, 0};
        *(i32x4*)(sm + slot * LDSROW + pl * 128 + SWZ(pl, ci0)) = z;
    }
    __syncthreads();

    #pragma unroll 1
    for (int t = 0; t < TPB; ++t) {
        int ph = ph0 + t;
        int id = blockIdx.x * TPB + t;

        i32x4 stv;
        int stdst = -1;
        if (t < TPB - 1 && threadIdx.x < 464) {
            int nrow = ph + 2;              // <= 57: in-bounds (prep zeroed row 57)
            int off = threadIdx.x * 16;
            int p = off >> 7, ci0 = off & 127;
            stv = *(const i32x4*)(xi8 + (size_t)b * XBATCH + (size_t)nrow * XROW + off);
            int pl = p + 1;
            stdst = (nrow & 3) * LDSROW + pl * 128 + SWZ(pl, ci0);
        }

        int rs[3] = { ((ph - 1) & 3) * LDSROW, (ph & 3) * LDSROW, ((ph + 1) & 3) * LDSROW };

        i32x16 acc0 = {}, acc1 = {};
        #pragma unroll
        for (int q = 0; q < 36; ++q) {
            int tap = q >> 2, kk = q & 3;
            int dh = tap / 3, dw = tap % 3;
            i32x4 a = *(const i32x4*)(sm + rs[dh] + coff[dw][kk]);
            if (q & 1) mfma_i8(acc1, a, bfr[q]);
            else       mfma_i8(acc0, a, bfr[q]);
        }
        asm volatile("s_nop 7\n\ts_nop 7\n\ts_nop 7" : "+v"(acc0), "+v"(acc1));
        #pragma unroll
        for (int e = 0; e < 16; ++e) acc0[e] += acc1[e];

        unsigned s1 = 0, s2 = 0;
        #pragma unroll
        for (int reg = 0; reg < 16; ++reg) {
            int pw = 32 * sh + (reg & 3) + 8 * (reg >> 2) + 4 * hi;
            int y = acc0[reg];
            int r = y > 0 ? y : 0;
            if (pw >= 1 && pw <= WW) {
                s1 += (unsigned)r;
                s2 += (unsigned)__mul24(r, r);
            }
        }
        s1 += __shfl_xor(s1, 32);
        s2 += __shfl_xor(s2, 32);
        if (hi == 0) {
            int slot = id & (NSLOT - 1);
            atomicAdd(&accum[slot * 256 + co],       (unsigned long long)s1);
            atomicAdd(&accum[slot * 256 + 128 + co], (unsigned long long)s2);
        }

        if (stdst >= 0) *(i32x4*)(sm + stdst) = stv;
        __syncthreads();
    }
}

// ---------------- gemm2: conv recompute + BN + shortcut, LDS-bounce epilogue ----------------
// (448 blocks x 4 tiles; inner code verbatim R17)
__global__ __launch_bounds__(512) void gemm2_k(const signed char* __restrict__ xi8,
                                               const signed char* __restrict__ wfrag,
                                               const unsigned long long* __restrict__ accum,
                                               const float* __restrict__ gamma,
                                               const float* __restrict__ beta,
                                               const float* __restrict__ x,
                                               float* __restrict__ out) {
    __shared__ alignas(16) char sm[4 * LDSROW];      // 33,792 B
    __shared__ unsigned short r_lds[WW * CH];        // 14,336 B
    __shared__ float2 ssl[CH];                       //  1,024 B  (total 48 KiB)

    int ph0 = 1 + ((blockIdx.x * TPB) % HH);
    int b   = (blockIdx.x * TPB) / HH;

    int L = threadIdx.x & 63, w = threadIdx.x >> 6;
    int n32 = w & 3, sh = w >> 2;
    int l31 = L & 31, hi = L >> 5;

    int coff[3][4];
    #pragma unroll
    for (int dw = 0; dw < 3; ++dw) {
        int pld = l31 + dw;
        int pl = 32 * sh + pld;
        #pragma unroll
        for (int kk = 0; kk < 4; ++kk)
            coff[dw][kk] = pl * 128 + ((32 * kk + 16 * hi) ^ ((pld & 7) << 4));
    }

    const i32x4* bfp = (const i32x4*)wfrag + (size_t)n32 * 36 * 64;
    i32x4 bfr[36];
    #pragma unroll
    for (int q = 0; q < 36; ++q) bfr[q] = bfp[q * 64 + L];

    int co = 32 * n32 + l31;

    for (int c = threadIdx.x; c < 1392; c += 512) {
        int rr = c / 464;
        int off = (c % 464) * 16;
        int row = ph0 - 1 + rr;
        int p = off >> 7, ci0 = off & 127;
        i32x4 v = *(const i32x4*)(xi8 + (size_t)b * XBATCH + (size_t)row * XROW + off);
        int pl = p + 1;
        *(i32x4*)(sm + (row & 3) * LDSROW + pl * 128 + SWZ(pl, ci0)) = v;
    }
    if (threadIdx.x < 256) {
        int slot = threadIdx.x >> 6, g = threadIdx.x & 63;
        int gp = g >> 3, ci0 = (g & 7) * 16;
        int pl = (gp == 0) ? 0 : (58 + gp);
        i32x4 z = {0, 0, 0, 0};
        *(i32x4*)(sm + slot * LDSROW + pl * 128 + SWZ(pl, ci0)) = z;
    }
    if (threadIdx.x < CH) {     // per-block BN finalize (exact integer sums -> f32)
        int c = threadIdx.x;
        unsigned long long a1 = 0, a2 = 0;
        #pragma unroll
        for (int s = 0; s < NSLOT; ++s) {
            a1 += accum[s * 256 + c];
            a2 += accum[s * 256 + 128 + c];
        }
        float N    = (float)NPIX;
        float mean = (float)a1 / N;
        float ex2  = (float)a2 / N;
        float var  = fmaf(-mean, mean, ex2);
        float rstd = 1.0f / sqrtf(var + 1e-3f);
        float sc   = gamma[c] * rstd;
        float2 v;
        v.x = sc;
        v.y = fmaf(-mean, sc, beta[c]);
        ssl[c] = v;
    }
    __syncthreads();

    // per-thread streaming constants (channel group is iteration-invariant)
    int c40 = (threadIdx.x & 31) * 4;
    float2 t0 = ssl[c40 + 0], t1 = ssl[c40 + 1];
    float2 t2 = ssl[c40 + 2], t3 = ssl[c40 + 3];

    #pragma unroll 1
    for (int t = 0; t < TPB; ++t) {
        int ph = ph0 + t;

        i32x4 stv;
        int stdst = -1;
        if (t < TPB - 1 && threadIdx.x < 464) {
            int nrow = ph + 2;
            int off = threadIdx.x * 16;
            int p = off >> 7, ci0 = off & 127;
            stv = *(const i32x4*)(xi8 + (size_t)b * XBATCH + (size_t)nrow * XROW + off);
            int pl = p + 1;
            stdst = (nrow & 3) * LDSROW + pl * 128 + SWZ(pl, ci0);
        }

        int rs[3] = { ((ph - 1) & 3) * LDSROW, (ph & 3) * LDSROW, ((ph + 1) & 3) * LDSROW };

        i32x16 acc0 = {}, acc1 = {};
        #pragma unroll
        for (int q = 0; q < 36; ++q) {
            int tap = q >> 2, kk = q & 3;
            int dh = tap / 3, dw = tap % 3;
            i32x4 a = *(const i32x4*)(sm + rs[dh] + coff[dw][kk]);
            if (q & 1) mfma_i8(acc1, a, bfr[q]);
            else       mfma_i8(acc0, a, bfr[q]);
        }
        asm volatile("s_nop 7\n\ts_nop 7\n\ts_nop 7" : "+v"(acc0), "+v"(acc1));
        #pragma unroll
        for (int e = 0; e < 16; ++e) acc0[e] += acc1[e];

        // acc -> r_lds (u16), same (pw,co) mapping as the proven rb store
        #pragma unroll
        for (int reg = 0; reg < 16; ++reg) {
            int pw = 32 * sh + (reg & 3) + 8 * (reg >> 2) + 4 * hi;
            int y = acc0[reg];
            if (pw >= 1 && pw <= WW)
                r_lds[(pw - 1) * CH + co] = (unsigned short)(y > 0 ? y : 0);
        }
        __syncthreads();   // r_lds complete before streaming

        // coalesced stream: ushort4 (LDS) + float4 (x) -> float4 (out)
        size_t row4 = (size_t)(b * HH + ph - 1) * (WW * CH / 4);
        for (int i = threadIdx.x; i < WW * CH / 4; i += 512) {
            ushort4 rv = ((const ushort4*)r_lds)[i];
            float4 xv = ((const float4*)x)[row4 + i];
            float4 o;
            o.x = fmaf((float)rv.x, t0.x, t0.y + xv.x);
            o.y = fmaf((float)rv.y, t1.x, t1.y + xv.y);
            o.z = fmaf((float)rv.z, t2.x, t2.y + xv.z);
            o.w = fmaf((float)rv.w, t3.x, t3.y + xv.w);
            ((float4*)out)[row4 + i] = o;
        }

        if (stdst >= 0) *(i32x4*)(sm + stdst) = stv;
        __syncthreads();   // fences: r_lds/sm readers done + staged row visible
    }
}

extern "C" void kernel_launch(void* const* d_in, const int* in_sizes, int n_in,
                              void* d_out, int out_size, void* d_ws, size_t ws_size,
                              hipStream_t stream) {
    const float* x     = (const float*)d_in[0];
    const float* Wt    = (const float*)d_in[1];
    const float* gamma = (const float*)d_in[2];
    const float* beta  = (const float*)d_in[3];
    float* out = (float*)d_out;
    char* ws = (char*)d_ws;

    signed char* xi8   = (signed char*)ws;                            // 13,778,944
    signed char* wfrag = (signed char*)(ws + 13778944);               //    147,456
    unsigned long long* accum = (unsigned long long*)(ws + 13926400); //     32,768

    hipLaunchKernelGGL(prep_k,  dim3(12809), dim3(256), 0, stream, x, Wt, xi8, wfrag, accum);
    hipLaunchKernelGGL(gemm1_k, dim3(NBLK),  dim3(512), 0, stream, xi8, wfrag, accum);
    hipLaunchKernelGGL(gemm2_k, dim3(NBLK),  dim3(512), 0, stream, xi8, wfrag, accum,
                       gamma, beta, x, out);
}

// Round 19
// 59.155 us; speedup vs baseline: 1.5267x; 1.5267x over previous
//
#include <hip/hip_runtime.h>

#define CH    128
#define HH    56
#define WW    56
#define BB    32
#define NPIX  (BB * HH * WW)   // 100352
#define NSLOT 16

#define XROW   7424            // 58 cols * 128 ci, bytes per padded row
#define XBATCH 430592          // 58 rows * XROW
#define LDSROW 8448            // per row-slot: 8 planes x 1056 B
#define PLANE  1056            // 66 pixels * 16 B

typedef int i32x4  __attribute__((ext_vector_type(4)));
typedef int i32x16 __attribute__((ext_vector_type(16)));

__device__ __forceinline__ void mfma_i8(i32x16& acc, i32x4 a, i32x4 b) {
    asm("v_mfma_i32_32x32x32_i8 %0, %1, %2, %0" : "+v"(acc) : "v"(a), "v"(b));
}

// ---------------- prep: xi8 signs + borders + wfrag + accum zero ----------------
// (verbatim from the passing R10..R18 kernels)
__global__ __launch_bounds__(256) void prep_k(const float* __restrict__ x,
                                              const float* __restrict__ Wt,
                                              signed char* __restrict__ xi8,
                                              signed char* __restrict__ wfrag,
                                              unsigned long long* __restrict__ accum) {
    int bx = blockIdx.x, tid = threadIdx.x;
    if (bx < 12544) {                       // interior signs: one float4 -> 4 int8
        int t = bx * 256 + tid;             // < 3,211,264
        int p = t >> 5;
        int ci0 = (t & 31) * 4;
        int w = p % WW;
        int t2 = p / WW;
        int h = t2 % HH;
        int b = t2 / HH;
        float4 v = ((const float4*)x)[t];
        unsigned o = (v.x >= 0.f ? 0x01u : 0xFFu)
                   | ((v.y >= 0.f ? 0x01u : 0xFFu) << 8)
                   | ((v.z >= 0.f ? 0x01u : 0xFFu) << 16)
                   | ((v.w >= 0.f ? 0x01u : 0xFFu) << 24);
        *(unsigned*)(xi8 + (size_t)b * XBATCH + (size_t)(h + 1) * XROW + (w + 1) * 128 + ci0) = o;
    } else if (bx < 12772) {                // border zeros: 58368 16B chunks
        int c = (bx - 12544) * 256 + tid;
        int cell = c >> 3, q = c & 7;
        int b = cell / 228, e = cell % 228;
        int row, col;
        if (e < 58)       { row = 0;       col = e; }
        else if (e < 116) { row = 57;      col = e - 58; }
        else if (e < 172) { row = e - 115; col = 0; }
        else              { row = e - 171; col = 57; }
        i32x4 z = {0, 0, 0, 0};
        *(i32x4*)(xi8 + (size_t)b * XBATCH + (size_t)row * XROW + col * 128 + q * 16) = z;
    } else if (bx < 12808) {                // wfrag: [n32][q=36][lane][16B]
        int i = (bx - 12772) * 256 + tid;   // < 9216
        int n = i / 2304;
        int r = i % 2304;
        int q = r / 64;
        int L = r % 64;
        int tap = q >> 2, kk = q & 3;
        int co = 32 * n + (L & 31);
        int kbase = 32 * kk + (L >> 5) * 16;
        i32x4 o;
        #pragma unroll
        for (int d = 0; d < 4; ++d) {
            unsigned u = 0;
            #pragma unroll
            for (int by = 0; by < 4; ++by) {
                int ci = kbase + 4 * d + by;
                unsigned s = (Wt[((size_t)tap * 128 + ci) * 128 + co] >= 0.f) ? 0x01u : 0xFFu;
                u |= s << (8 * by);
            }
            o[d] = (int)u;
        }
        *(i32x4*)(wfrag + (size_t)i * 16) = o;
    } else {                                // accum zero
        for (int k = tid; k < NSLOT * 256; k += 256) accum[k] = 0ull;
    }
}

// ---------------- persistent gemm: rolling 4-row window, PLANAR LDS ----------------
// Identical structure to the 60.4us R15 kernel; only the LDS address bijection
// changed: row-slot holds 8 planes [c16 = 2kk+hi][pixel 0..65] of 16B chunks.
// A-read for (kk,hi): lane addresses sequential 16B -> zero bank conflicts.
// Staging: global src unchanged (coalesced, off = c*16); dst 2-way (free).
__global__ __launch_bounds__(512) void gemm_k(const signed char* __restrict__ xi8,
                                              const signed char* __restrict__ wfrag,
                                              unsigned long long* __restrict__ accum,
                                              unsigned short* __restrict__ rb) {
    __shared__ alignas(16) char sm[4 * LDSROW];   // 33,792 B

    int ph0 = 1 + ((blockIdx.x * 7) % HH);        // first padded row
    int b   = (blockIdx.x * 7) / HH;              // batch (constant per block)

    int L = threadIdx.x & 63, w = threadIdx.x >> 6;
    int n32 = w & 3, sh = w >> 2;
    int l31 = L & 31, hi = L >> 5;

    // planar A-read byte offsets (tile-invariant): plane (2kk+hi), pixel 32sh+l31+dw
    int coff[3][4];
    #pragma unroll
    for (int dw = 0; dw < 3; ++dw) {
        int px = 32 * sh + l31 + dw;
        #pragma unroll
        for (int kk = 0; kk < 4; ++kk)
            coff[dw][kk] = (2 * kk + hi) * PLANE + px * 16;
    }

    // hoist ALL B fragments for this wave's co-slice (144 VGPR)
    const i32x4* bfp = (const i32x4*)wfrag + (size_t)n32 * 36 * 64;
    i32x4 bfr[36];
    #pragma unroll
    for (int q = 0; q < 36; ++q) bfr[q] = bfp[q * 64 + L];

    int co = 32 * n32 + l31;

    // ---- prologue: stage rows ph0-1..ph0+1 into slots (row&3); guards for all 4 slots ----
    for (int c = threadIdx.x; c < 1392; c += 512) {
        int rr = c / 464;
        int cc = c % 464;                         // chunk within row: pixel cc>>3, plane cc&7
        int row = ph0 - 1 + rr;
        i32x4 v = *(const i32x4*)(xi8 + (size_t)b * XBATCH + (size_t)row * XROW + cc * 16);
        *(i32x4*)(sm + (row & 3) * LDSROW + (cc & 7) * PLANE + ((cc >> 3) + 1) * 16) = v;
    }
    if (threadIdx.x < 256) {     // guard pixels {0, 59..65} zero, all 8 planes, all 4 slots
        int slot = threadIdx.x >> 6, g = threadIdx.x & 63;
        int plane = g >> 3, gp = g & 7;
        int pl = (gp == 0) ? 0 : (58 + gp);
        i32x4 z = {0, 0, 0, 0};
        *(i32x4*)(sm + slot * LDSROW + plane * PLANE + pl * 16) = z;
    }
    __syncthreads();

    #pragma unroll 1
    for (int t = 0; t < 7; ++t) {
        int ph = ph0 + t;
        int id = blockIdx.x * 7 + t;

        // issue next row's loads EARLY (written to LDS after the epilogue)
        i32x4 stv;
        int stdst = -1;
        if (t < 6 && threadIdx.x < 464) {
            int nrow = ph + 2;                       // <= 57: in-bounds (prep zeroed row 57)
            int cc = threadIdx.x;
            stv = *(const i32x4*)(xi8 + (size_t)b * XBATCH + (size_t)nrow * XROW + cc * 16);
            stdst = (nrow & 3) * LDSROW + (cc & 7) * PLANE + ((cc >> 3) + 1) * 16;
        }

        int rs[3] = { ((ph - 1) & 3) * LDSROW, (ph & 3) * LDSROW, ((ph + 1) & 3) * LDSROW };

        i32x16 acc0 = {}, acc1 = {};                 // 2 chains: break MFMA dep-latency
        #pragma unroll
        for (int q = 0; q < 36; ++q) {
            int tap = q >> 2, kk = q & 3;
            int dh = tap / 3, dw = tap % 3;
            i32x4 a = *(const i32x4*)(sm + rs[dh] + coff[dw][kk]);
            if (q & 1) mfma_i8(acc1, a, bfr[q]);
            else       mfma_i8(acc0, a, bfr[q]);
        }
        // MFMA -> VALU hazard fence, dependent on accs so it can't be hoisted
        asm volatile("s_nop 7\n\ts_nop 7\n\ts_nop 7" : "+v"(acc0), "+v"(acc1));
        #pragma unroll
        for (int e = 0; e < 16; ++e) acc0[e] += acc1[e];

        unsigned s1 = 0, s2 = 0;
        size_t rbase = (((size_t)b * HH + (ph - 1)) * WW) * CH + co;   // + (pw-1)*CH
        #pragma unroll
        for (int reg = 0; reg < 16; ++reg) {
            int pw = 32 * sh + (reg & 3) + 8 * (reg >> 2) + 4 * hi;
            int y = acc0[reg];
            int r = y > 0 ? y : 0;
            if (pw >= 1 && pw <= WW) {
                s1 += (unsigned)r;
                s2 += (unsigned)__mul24(r, r);
                rb[rbase + (size_t)(pw - 1) * CH] = (unsigned short)r;
            }
        }
        s1 += __shfl_xor(s1, 32);
        s2 += __shfl_xor(s2, 32);
        if (hi == 0) {
            int slot = id & (NSLOT - 1);
            atomicAdd(&accum[slot * 256 + co],       (unsigned long long)s1);
            atomicAdd(&accum[slot * 256 + 128 + co], (unsigned long long)s2);
        }

        // late LDS write of the prefetched row (load long since returned)
        if (stdst >= 0) *(i32x4*)(sm + stdst) = stv;

        __syncthreads();   // fences: MFMA readers done + staged row visible
    }
}

// ---------------- out: fused BN finalize + streaming epilogue ----------------
// (verbatim R13..R15) Threads 0..127 compute per-channel scale/shift from exact
// integer sums (f32 ample), then 8 float4 iterations.
__global__ __launch_bounds__(256) void out_k(const unsigned short* __restrict__ rb,
                                             const unsigned long long* __restrict__ accum,
                                             const float* __restrict__ gamma,
                                             const float* __restrict__ beta,
                                             const float* __restrict__ x,
                                             float* __restrict__ out) {
    __shared__ float2 ssl[CH];
    int tid = threadIdx.x;
    if (tid < CH) {
        unsigned long long a1 = 0, a2 = 0;
        #pragma unroll
        for (int s = 0; s < NSLOT; ++s) {
            a1 += accum[s * 256 + tid];
            a2 += accum[s * 256 + 128 + tid];
        }
        float N    = (float)NPIX;
        float mean = (float)a1 / N;
        float ex2  = (float)a2 / N;
        float var  = fmaf(-mean, mean, ex2);
        float rstd = 1.0f / sqrtf(var + 1e-3f);
        float sc   = gamma[tid] * rstd;
        float2 v;
        v.x = sc;
        v.y = fmaf(-mean, sc, beta[tid]);
        ssl[tid] = v;
    }
    __syncthreads();

    int c4 = tid & 31;
    float2 s0 = ssl[c4 * 4 + 0], s1 = ssl[c4 * 4 + 1];
    float2 s2 = ssl[c4 * 4 + 2], s3 = ssl[c4 * 4 + 3];
    int base = blockIdx.x * 2048 + tid;
    #pragma unroll
    for (int k = 0; k < 8; ++k) {
        int idx4 = base + k * 256;
        ushort4 r = ((const ushort4*)rb)[idx4];
        float4 xv = ((const float4*)x)[idx4];
        float4 o;
        o.x = fmaf((float)r.x, s0.x, s0.y + xv.x);
        o.y = fmaf((float)r.y, s1.x, s1.y + xv.y);
        o.z = fmaf((float)r.z, s2.x, s2.y + xv.z);
        o.w = fmaf((float)r.w, s3.x, s3.y + xv.w);
        ((float4*)out)[idx4] = o;
    }
}

extern "C" void kernel_launch(void* const* d_in, const int* in_sizes, int n_in,
                              void* d_out, int out_size, void* d_ws, size_t ws_size,
                              hipStream_t stream) {
    const float* x     = (const float*)d_in[0];
    const float* Wt    = (const float*)d_in[1];
    const float* gamma = (const float*)d_in[2];
    const float* beta  = (const float*)d_in[3];
    float* out = (float*)d_out;
    char* ws = (char*)d_ws;

    signed char* xi8   = (signed char*)ws;                            // 13,778,944
    signed char* wfrag = (signed char*)(ws + 13778944);               //    147,456
    unsigned long long* accum = (unsigned long long*)(ws + 13926400); //     32,768
    unsigned short* rb = (unsigned short*)(ws + 13959168);            // 25,690,112

    hipLaunchKernelGGL(prep_k, dim3(12809), dim3(256), 0, stream, x, Wt, xi8, wfrag, accum);
    hipLaunchKernelGGL(gemm_k, dim3(256),   dim3(512), 0, stream, xi8, wfrag, accum, rb);
    hipLaunchKernelGGL(out_k,  dim3(NPIX * CH / 4 / 2048), dim3(256), 0, stream,
                       rb, accum, gamma, beta, x, out);
}